// Round 1
// baseline (2517.322 us; speedup 1.0000x reference)
//
#include <hip/hip_runtime.h>
#include <hip/hip_bf16.h>
#include <hip/hip_fp16.h>

// Problem: B=2, S=2048, D_MODEL=1024, H=16, HD=64. Causal MHA with RoPE.
// Pipeline:
//   cast_kernel:  x f32 -> bf16 (Xc)
//   trans_kernel: wq/wk/wv/wo f32 [k][n] -> bf16 Wt[n][k] (n-major for B-frags)
//   gemm_kernel:  bf16 MFMA 128x128 tile; modes 0/1 fuse RoPE, write Q/K f32
//                 [bh][s][d]; mode 2 writes V; mode 3 writes d_out f32.
//   attn_kernel:  vector-f32 flash attn, lane=q-row, 4 waves split key tiles,
//                 LDS merge; writes attn output as bf16 [4096][1024].
// ws layout (72 MB): Xc 8MB | Wt 8MB | Q 16MB | K 16MB | V 16MB | AttnC 8MB

#define S_ 2048
#define DM 1024
#define HD 64

typedef __attribute__((ext_vector_type(8))) short short8;   // 8 bf16 (4 VGPRs)
typedef __attribute__((ext_vector_type(4))) float floatx4;  // 4 f32 acc

__device__ __forceinline__ unsigned short f2b(float x) {
  union { __hip_bfloat16 h; unsigned short u; } cv;
  cv.h = __float2bfloat16(x);
  return cv.u;
}

// ---------------- cast x f32 -> bf16 ----------------
__global__ void cast_kernel(const float* __restrict__ in,
                            unsigned short* __restrict__ out, int n) {
  int i = (blockIdx.x * blockDim.x + threadIdx.x) * 4;
  if (i >= n) return;
  float4 v = *(const float4*)(in + i);
  ushort4 o;
  o.x = f2b(v.x); o.y = f2b(v.y); o.z = f2b(v.z); o.w = f2b(v.w);
  *(ushort4*)(out + i) = o;
}

// ---------------- transpose + cast weights: Wt[n][k] = W[k][n] ----------------
__global__ void trans_kernel(const float* __restrict__ w0, const float* __restrict__ w1,
                             const float* __restrict__ w2, const float* __restrict__ w3,
                             unsigned short* __restrict__ wt) {
  __shared__ float tile[32][33];
  const float* W = (blockIdx.z == 0) ? w0 : (blockIdx.z == 1) ? w1
                   : (blockIdx.z == 2) ? w2 : w3;
  unsigned short* Wt = wt + (size_t)blockIdx.z * DM * DM;
  const int tx = threadIdx.x & 31;
  const int ty = threadIdx.x >> 5;       // 0..7
  const int k0 = blockIdx.x * 32;
  const int c0 = blockIdx.y * 32;
#pragma unroll
  for (int i = 0; i < 4; ++i)
    tile[ty + i * 8][tx] = W[(size_t)(k0 + ty + i * 8) * DM + c0 + tx];
  __syncthreads();
#pragma unroll
  for (int i = 0; i < 4; ++i)
    Wt[(size_t)(c0 + ty + i * 8) * DM + k0 + tx] = f2b(tile[tx][ty + i * 8]);
}

// ---------------- bf16 MFMA GEMM, 128x128 tile, 4 waves ----------------
// A: [4096][1024] bf16 row-major. Bt: [1024][1024] bf16, Bt[n][k].
// mode 0/1: +bias, RoPE, write f32 [bh][s][d] (Q/K)
// mode 2:   +bias, write f32 [bh][s][d] (V)
// mode 3:   +bias, write f32 [r][c] (d_out)
__global__ __launch_bounds__(256, 2) void gemm_kernel(
    const unsigned short* __restrict__ A, const unsigned short* __restrict__ Bt,
    const float* __restrict__ bias, float* __restrict__ out, const int mode) {
  __shared__ unsigned short As[128 * 40];  // 32 data + 8 pad shorts per row
  __shared__ unsigned short Bs[128 * 40];
  const int r0 = blockIdx.x * 128;
  const int c0 = blockIdx.y * 128;
  const int t = threadIdx.x;
  const int lane = t & 63;
  const int wvid = t >> 6;
  const int wr = (wvid >> 1) * 64;
  const int wc = (wvid & 1) * 64;
  const int arow = t >> 1;
  const int aseg = (t & 1) * 16;

  const unsigned short* Ag = A + (size_t)(r0 + arow) * DM + aseg;
  const unsigned short* Bg = Bt + (size_t)(c0 + arow) * DM + aseg;
  unsigned short* Asw = &As[arow * 40 + aseg];
  unsigned short* Bsw = &Bs[arow * 40 + aseg];

  floatx4 acc[4][4] = {};
  const int rr = lane & 15;
  const int kg = (lane >> 4) * 8;

  for (int k0 = 0; k0 < DM; k0 += 32) {
    __syncthreads();
    int4 a0 = *(const int4*)(Ag + k0);
    int4 a1 = *(const int4*)(Ag + k0 + 8);
    int4 b0 = *(const int4*)(Bg + k0);
    int4 b1 = *(const int4*)(Bg + k0 + 8);
    *(int4*)(Asw) = a0;
    *(int4*)(Asw + 8) = a1;
    *(int4*)(Bsw) = b0;
    *(int4*)(Bsw + 8) = b1;
    __syncthreads();
    short8 af[4], bf[4];
#pragma unroll
    for (int m = 0; m < 4; ++m)
      af[m] = *(const short8*)(&As[(wr + m * 16 + rr) * 40 + kg]);
#pragma unroll
    for (int n = 0; n < 4; ++n)
      bf[n] = *(const short8*)(&Bs[(wc + n * 16 + rr) * 40 + kg]);
#pragma unroll
    for (int m = 0; m < 4; ++m)
#pragma unroll
      for (int n = 0; n < 4; ++n)
        acc[m][n] = __builtin_amdgcn_mfma_f32_16x16x32_bf16(af[m], bf[n], acc[m][n], 0, 0, 0);
  }

  // epilogue: C row = r0+wr + m*16 + (lane>>4)*4 + i ; col = c0+wc + n*16 + (lane&15)
  const int rbase = r0 + wr + (lane >> 4) * 4;
  const int cbase = c0 + wc + rr;
#pragma unroll
  for (int n = 0; n < 4; ++n) {
    const int c = cbase + n * 16;
    const float bv = bias[c];
    const int d = c & 63;
    // theta = 10000^(-(d&~1)/64) ; same for the (even,odd) pair
    const float th = expf(-(float)(d & ~1) * (9.210340371976184f / 64.0f));
#pragma unroll
    for (int m = 0; m < 4; ++m) {
#pragma unroll
      for (int i = 0; i < 4; ++i) {
        const int r = rbase + m * 16 + i;
        float v = acc[m][n][i] + bv;
        float pv = __shfl_xor(v, 1);  // partner column (d^1), same row
        if (mode < 2) {
          const int s = r & (S_ - 1);
          float sn, cs;
          sincosf((float)s * th, &sn, &cs);
          v = (d & 1) ? fmaf(v, cs, pv * sn) : fmaf(v, cs, -pv * sn);
        }
        if (mode == 3) {
          out[(size_t)r * DM + c] = v;
        } else {
          const int b = r >> 11;
          const int s = r & (S_ - 1);
          const int h = c >> 6;
          out[((size_t)((b << 4) | h) * S_ + s) * HD + d] = v;
        }
      }
    }
  }
}

// ---------------- flash attention, vector f32 ----------------
// grid: (bh=32, qt=32), block 256 = 4 waves. lane = q row within 64-row tile.
// Wave w handles key tiles t = w, w+4, ... <= qt; partials merged via LDS.
__global__ __launch_bounds__(256, 2) void attn_kernel(
    const float* __restrict__ Q, const float* __restrict__ K,
    const float* __restrict__ V, unsigned short* __restrict__ AttnC) {
  extern __shared__ char smem_raw[];
  __half* Om = (__half*)smem_raw;                       // [4][64][66] halves
  float* Ml = (float*)(smem_raw + 4 * 64 * 66 * 2);     // [4][64][2]

  const int bh = blockIdx.x;  // b*16 + h
  const int qt = blockIdx.y;
  const int tid = threadIdx.x;
  const int w = tid >> 6;
  const int l = tid & 63;
  const int row = qt * 64 + l;
  const size_t base = (size_t)bh * S_ * HD;

  float q[64];
  {
    const float4* Qp = (const float4*)(Q + base + (size_t)row * HD);
#pragma unroll
    for (int dc = 0; dc < 16; ++dc) {
      float4 t4 = Qp[dc];
      q[dc * 4 + 0] = t4.x * 0.125f;
      q[dc * 4 + 1] = t4.y * 0.125f;
      q[dc * 4 + 2] = t4.z * 0.125f;
      q[dc * 4 + 3] = t4.w * 0.125f;
    }
  }
  float O[64];
#pragma unroll
  for (int d = 0; d < 64; ++d) O[d] = 0.f;
  float m = -1e30f, lsum = 0.f;

#pragma unroll 1
  for (int t = w; t <= qt; t += 4) {
    const float4* K4 = (const float4*)(K + base + (size_t)t * 64 * HD);
    const float4* V4 = (const float4*)(V + base + (size_t)t * 64 * HD);
    const bool diag = (t == qt);
#pragma unroll 1
    for (int ks = 0; ks < 4; ++ks) {
      float sc[16];
#pragma unroll
      for (int jj = 0; jj < 16; ++jj) {
        const float4* kp = K4 + (ks * 16 + jj) * 16;
        float a0 = 0.f, a1 = 0.f, a2 = 0.f, a3 = 0.f;
#pragma unroll
        for (int dc = 0; dc < 16; ++dc) {
          float4 kv = kp[dc];
          a0 = fmaf(q[dc * 4 + 0], kv.x, a0);
          a1 = fmaf(q[dc * 4 + 1], kv.y, a1);
          a2 = fmaf(q[dc * 4 + 2], kv.z, a2);
          a3 = fmaf(q[dc * 4 + 3], kv.w, a3);
        }
        sc[jj] = (a0 + a1) + (a2 + a3);
      }
      if (diag) {
#pragma unroll
        for (int jj = 0; jj < 16; ++jj)
          if (ks * 16 + jj > l) sc[jj] = -1e30f;
      }
      float tm = sc[0];
#pragma unroll
      for (int jj = 1; jj < 16; ++jj) tm = fmaxf(tm, sc[jj]);
      const float mn = fmaxf(m, tm);
      const float alpha = __expf(m - mn);
      lsum *= alpha;
#pragma unroll
      for (int d = 0; d < 64; ++d) O[d] *= alpha;
      m = mn;
#pragma unroll
      for (int jj = 0; jj < 16; ++jj) {
        const float pj = __expf(sc[jj] - mn);
        lsum += pj;
        const float4* vp = V4 + (ks * 16 + jj) * 16;
#pragma unroll
        for (int dc = 0; dc < 16; ++dc) {
          float4 vv = vp[dc];
          O[dc * 4 + 0] = fmaf(pj, vv.x, O[dc * 4 + 0]);
          O[dc * 4 + 1] = fmaf(pj, vv.y, O[dc * 4 + 1]);
          O[dc * 4 + 2] = fmaf(pj, vv.z, O[dc * 4 + 2]);
          O[dc * 4 + 3] = fmaf(pj, vv.w, O[dc * 4 + 3]);
        }
      }
    }
  }

  // write partials (f16 O, f32 m/l)
#pragma unroll
  for (int d = 0; d < 64; ++d) Om[(w * 64 + l) * 66 + d] = __float2half(O[d]);
  Ml[(w * 64 + l) * 2 + 0] = m;
  Ml[(w * 64 + l) * 2 + 1] = lsum;
  __syncthreads();

  // merge: wave w handles output dims [w*16, w*16+16) for all 64 rows
  float mm[4], ll[4];
  float M = -1e30f;
#pragma unroll
  for (int p = 0; p < 4; ++p) {
    mm[p] = Ml[(p * 64 + l) * 2 + 0];
    ll[p] = Ml[(p * 64 + l) * 2 + 1];
    M = fmaxf(M, mm[p]);
  }
  float ep[4];
  float L = 0.f;
#pragma unroll
  for (int p = 0; p < 4; ++p) {
    ep[p] = __expf(mm[p] - M);
    L += ll[p] * ep[p];
  }
  const float invL = 1.f / L;
  unsigned int outw[8];
#pragma unroll
  for (int dd = 0; dd < 16; dd += 2) {
    const int d0 = w * 16 + dd;
    float o0 = 0.f, o1 = 0.f;
#pragma unroll
    for (int p = 0; p < 4; ++p) {
      o0 += ep[p] * __half2float(Om[(p * 64 + l) * 66 + d0]);
      o1 += ep[p] * __half2float(Om[(p * 64 + l) * 66 + d0 + 1]);
    }
    o0 *= invL;
    o1 *= invL;
    outw[dd / 2] = (unsigned int)f2b(o0) | ((unsigned int)f2b(o1) << 16);
  }
  unsigned short* orow =
      AttnC + (size_t)((bh >> 4) * S_ + row) * DM + (bh & 15) * HD + w * 16;
  *(uint4*)(orow) = make_uint4(outw[0], outw[1], outw[2], outw[3]);
  *(uint4*)(orow + 8) = make_uint4(outw[4], outw[5], outw[6], outw[7]);
}

extern "C" void kernel_launch(void* const* d_in, const int* in_sizes, int n_in,
                              void* d_out, int out_size, void* d_ws, size_t ws_size,
                              hipStream_t stream) {
  const float* x = (const float*)d_in[0];
  // d_in[1] = mask (causal, hardcoded)
  const float* wq = (const float*)d_in[2];
  const float* bq = (const float*)d_in[3];
  const float* wk = (const float*)d_in[4];
  const float* bk = (const float*)d_in[5];
  const float* wv = (const float*)d_in[6];
  const float* bv = (const float*)d_in[7];
  const float* wo = (const float*)d_in[8];
  const float* bo = (const float*)d_in[9];

  char* ws = (char*)d_ws;
  const size_t MB = 1024ull * 1024ull;
  unsigned short* Xc = (unsigned short*)(ws);            // 8 MB
  unsigned short* Wt = (unsigned short*)(ws + 8 * MB);   // 4 x 2 MB
  float* Qf = (float*)(ws + 16 * MB);                    // 16 MB
  float* Kf = (float*)(ws + 32 * MB);                    // 16 MB
  float* Vf = (float*)(ws + 48 * MB);                    // 16 MB
  unsigned short* Ac = (unsigned short*)(ws + 64 * MB);  // 8 MB

  cast_kernel<<<4096, 256, 0, stream>>>(x, Xc, 2 * S_ * DM);
  trans_kernel<<<dim3(32, 32, 4), 256, 0, stream>>>(wq, wk, wv, wo, Wt);
  gemm_kernel<<<dim3(32, 8), 256, 0, stream>>>(Xc, Wt + 0 * MB, bq, Qf, 0);
  gemm_kernel<<<dim3(32, 8), 256, 0, stream>>>(Xc, Wt + 1 * MB, bk, Kf, 1);
  gemm_kernel<<<dim3(32, 8), 256, 0, stream>>>(Xc, Wt + 2 * MB, bv, Vf, 2);
  attn_kernel<<<dim3(32, 32), 256, 35840, stream>>>(Qf, Kf, Vf, Ac);
  gemm_kernel<<<dim3(32, 8), 256, 0, stream>>>(Ac, Wt + 3 * MB, bo, (float*)d_out, 3);
}

// Round 2
// 203.306 us; speedup vs baseline: 12.3819x; 12.3819x over previous
//
#include <hip/hip_runtime.h>
#include <hip/hip_bf16.h>

// B=2, S=2048, D=1024, H=16, HD=64. Causal MHA + RoPE.
// cast -> trans -> 3x GEMM (bf16 out, RoPE fused) -> MFMA flash attn -> GEMM out.
// ws: Xc 8MB | Wt 8MB | Qb 8MB | Kb 8MB | Vb 8MB | Ac 8MB (all bf16)

#define S_ 2048
#define DM 1024
#define HD 64

typedef __attribute__((ext_vector_type(8))) short short8;   // 8 bf16
typedef __attribute__((ext_vector_type(4))) float floatx4;  // 4 f32

__device__ __forceinline__ unsigned short f2b(float x) {
  union { __hip_bfloat16 h; unsigned short u; } cv;
  cv.h = __float2bfloat16(x);
  return cv.u;
}

__device__ __forceinline__ void gload_lds16(const unsigned short* g, unsigned short* l) {
  typedef const __attribute__((address_space(1))) unsigned int* gp_t;
  typedef __attribute__((address_space(3))) unsigned int* lp_t;
  __builtin_amdgcn_global_load_lds((gp_t)(const void*)g, (lp_t)(void*)l, 16, 0, 0);
}

// ---------------- cast x f32 -> bf16 ----------------
__global__ void cast_kernel(const float* __restrict__ in,
                            unsigned short* __restrict__ out, int n) {
  int i = (blockIdx.x * blockDim.x + threadIdx.x) * 4;
  if (i >= n) return;
  float4 v = *(const float4*)(in + i);
  ushort4 o;
  o.x = f2b(v.x); o.y = f2b(v.y); o.z = f2b(v.z); o.w = f2b(v.w);
  *(ushort4*)(out + i) = o;
}

// ---------------- transpose + cast weights: Wt[n][k] = W[k][n] ----------------
__global__ void trans_kernel(const float* __restrict__ w0, const float* __restrict__ w1,
                             const float* __restrict__ w2, const float* __restrict__ w3,
                             unsigned short* __restrict__ wt) {
  __shared__ float tile[32][33];
  const float* W = (blockIdx.z == 0) ? w0 : (blockIdx.z == 1) ? w1
                   : (blockIdx.z == 2) ? w2 : w3;
  unsigned short* Wt = wt + (size_t)blockIdx.z * DM * DM;
  const int tx = threadIdx.x & 31;
  const int ty = threadIdx.x >> 5;
  const int k0 = blockIdx.x * 32;
  const int c0 = blockIdx.y * 32;
#pragma unroll
  for (int i = 0; i < 4; ++i)
    tile[ty + i * 8][tx] = W[(size_t)(k0 + ty + i * 8) * DM + c0 + tx];
  __syncthreads();
#pragma unroll
  for (int i = 0; i < 4; ++i)
    Wt[(size_t)(c0 + ty + i * 8) * DM + k0 + tx] = f2b(tile[tx][ty + i * 8]);
}

// ---------------- bf16 MFMA GEMM (m97 structure): 128x128 tile, BK=32 ----------------
// A: [4096][1024] bf16. Bt[n][k] bf16. mode 0/1: RoPE -> bf16 [bh][s][d].
// mode 2: bf16 [bh][s][d]. mode 3: f32 [r][c] (d_out).
__global__ __launch_bounds__(256, 2) void gemm_kernel(
    const unsigned short* __restrict__ A, const unsigned short* __restrict__ Bt,
    const float* __restrict__ bias, void* __restrict__ out, const int mode) {
  __shared__ __attribute__((aligned(16))) unsigned short As[128 * 32];
  __shared__ __attribute__((aligned(16))) unsigned short Bs[128 * 32];
  const int r0 = blockIdx.x * 128;
  const int c0 = blockIdx.y * 128;
  const int t = threadIdx.x;
  const int lane = t & 63;
  const int wv = t >> 6;
  const int wr = (wv >> 1) * 64;
  const int wc = (wv & 1) * 64;
  const int lr = lane & 15;
  const int lg = lane >> 4;

  // staging: wave wv stages rows [wv*32, wv*32+32) of both tiles
  const int srow = wv * 32 + (lane >> 2);
  const int sseg = (lane & 3) * 8;
  const unsigned short* Ag = A + (size_t)(r0 + srow) * DM + sseg;
  const unsigned short* Bg = Bt + (size_t)(c0 + srow) * DM + sseg;
  unsigned short* lA = &As[wv * 1024];
  unsigned short* lB = &Bs[wv * 1024];

  floatx4 acc[4][4] = {};

  for (int k0 = 0; k0 < DM; k0 += 32) {
    gload_lds16(Ag + k0, lA);
    gload_lds16(Ag + k0 + 16 * DM, lA + 512);
    gload_lds16(Bg + k0, lB);
    gload_lds16(Bg + k0 + 16 * DM, lB + 512);
    __syncthreads();
    short8 af[4], bf[4];
#pragma unroll
    for (int m = 0; m < 4; ++m)
      af[m] = *(const short8*)(&As[(wr + m * 16 + lr) * 32 + lg * 8]);
#pragma unroll
    for (int n = 0; n < 4; ++n)
      bf[n] = *(const short8*)(&Bs[(wc + n * 16 + lr) * 32 + lg * 8]);
#pragma unroll
    for (int m = 0; m < 4; ++m)
#pragma unroll
      for (int n = 0; n < 4; ++n)
        acc[m][n] = __builtin_amdgcn_mfma_f32_16x16x32_bf16(af[m], bf[n], acc[m][n], 0, 0, 0);
    __syncthreads();
  }

  // epilogue: row = r0+wr + m*16 + lg*4 + i ; col = c0+wc + n*16 + lr
  const int rbase = r0 + wr + lg * 4;
  const int cbase = c0 + wc + lr;
#pragma unroll
  for (int n = 0; n < 4; ++n) {
    const int c = cbase + n * 16;
    const float bv = bias[c];
    const int d = c & 63;
    const float th = expf(-(float)(d & ~1) * (9.210340371976184f / 64.0f));
#pragma unroll
    for (int m = 0; m < 4; ++m) {
#pragma unroll
      for (int i = 0; i < 4; ++i) {
        const int r = rbase + m * 16 + i;
        float v = acc[m][n][i] + bv;
        float pv = __shfl_xor(v, 1);
        if (mode < 2) {
          const int s = r & (S_ - 1);
          float sn, cs;
          sincosf((float)s * th, &sn, &cs);
          v = (d & 1) ? fmaf(v, cs, pv * sn) : fmaf(v, cs, -pv * sn);
        }
        if (mode == 3) {
          ((float*)out)[(size_t)r * DM + c] = v;
        } else {
          const int b = r >> 11;
          const int s = r & (S_ - 1);
          const int h = c >> 6;
          ((unsigned short*)out)[((size_t)((b << 4) | h) * S_ + s) * HD + d] = f2b(v);
        }
      }
    }
  }
}

// ---------------- MFMA flash attention ----------------
// grid (bh=32, 32 q-tiles reversed), 256 thr = 4 waves; wave w owns q rows
// [qt*64 + w*16, +16). K row-major swizzled; V transposed (Vt[d][k]) swizzled;
// P per-wave swizzled LDS tile for C-layout -> A-frag conversion.
__global__ __launch_bounds__(256, 4) void attn_kernel(
    const unsigned short* __restrict__ Q, const unsigned short* __restrict__ K,
    const unsigned short* __restrict__ V, unsigned short* __restrict__ AttnC) {
  __shared__ __attribute__((aligned(16))) unsigned short Ks[64 * 64];
  __shared__ __attribute__((aligned(16))) unsigned short Vs[64 * 64];
  __shared__ __attribute__((aligned(16))) unsigned short Ps[4 * 16 * 64];

  const int bh = blockIdx.x;
  const int qt = (int)(gridDim.y - 1) - (int)blockIdx.y;  // big blocks first
  const int tid = threadIdx.x;
  const int w = tid >> 6;
  const int l = tid & 63;
  const int lg = l >> 4;   // 0..3
  const int lr = l & 15;
  const size_t base = (size_t)bh * S_ * HD;

  // Q A-frags for this wave's 16 rows (row = lr, k = kk*32 + lg*8 + j)
  short8 qf[2];
  {
    const unsigned short* Qrow = Q + base + (size_t)(qt * 64 + w * 16 + lr) * HD + lg * 8;
    qf[0] = *(const short8*)(Qrow);
    qf[1] = *(const short8*)(Qrow + 32);
  }

  floatx4 o[4] = {};
  float m[4], lsum[4];
#pragma unroll
  for (int i = 0; i < 4; ++i) { m[i] = -1e30f; lsum[i] = 0.f; }

  const int krow = tid >> 3;   // 0..31
  const int kseg = tid & 7;

  for (int t = 0; t <= qt; ++t) {
    const unsigned short* Kg = K + base + (size_t)t * 64 * HD;
    const unsigned short* Vg = V + base + (size_t)t * 64 * HD;
    // stage K rows (swizzle byte_in_row ^= (row&7)<<4)
#pragma unroll
    for (int i = 0; i < 2; ++i) {
      int r = krow + i * 32;
      int4 kv = *(const int4*)(Kg + r * 64 + kseg * 8);
      *(int4*)((char*)Ks + r * 128 + ((kseg * 16) ^ ((r & 7) << 4))) = kv;
    }
    // stage V transposed: Vt[d][k], thread holds keys 2*krow,2*krow+1 dims kseg*8..+8
    {
      short8 a = *(const short8*)(Vg + (2 * krow) * 64 + kseg * 8);
      short8 b = *(const short8*)(Vg + (2 * krow) * 64 + 64 + kseg * 8);
#pragma unroll
      for (int j = 0; j < 8; ++j) {
        int d = kseg * 8 + j;
        unsigned int pk = (unsigned int)(unsigned short)a[j] |
                          ((unsigned int)(unsigned short)b[j] << 16);
        *(unsigned int*)((char*)Vs + d * 128 + ((4 * krow) ^ ((d & 7) << 4))) = pk;
      }
    }
    __syncthreads();

    // S = Q K^T (16 x 64): col frag n -> keys n*16+lr
    floatx4 s[4] = {};
#pragma unroll
    for (int kk = 0; kk < 2; ++kk) {
#pragma unroll
      for (int n = 0; n < 4; ++n) {
        int c = n * 16 + lr;
        short8 kb = *(const short8*)((char*)Ks + c * 128 +
                                     ((kk * 64 + lg * 16) ^ ((c & 7) << 4)));
        s[n] = __builtin_amdgcn_mfma_f32_16x16x32_bf16(qf[kk], kb, s[n], 0, 0, 0);
      }
    }
    if (t == qt) {  // causal mask on the diagonal tile
#pragma unroll
      for (int n = 0; n < 4; ++n)
#pragma unroll
        for (int i = 0; i < 4; ++i)
          if (n * 16 + lr > w * 16 + lg * 4 + i) s[n][i] = -1e30f;
    }

    // online softmax (row r = lg*4+i; reduce across the 16-lane col group)
    float al[4], ps[4];
#pragma unroll
    for (int i = 0; i < 4; ++i) {
      float v = fmaxf(fmaxf(s[0][i], s[1][i]), fmaxf(s[2][i], s[3][i]));
      v = fmaxf(v, __shfl_xor(v, 1));
      v = fmaxf(v, __shfl_xor(v, 2));
      v = fmaxf(v, __shfl_xor(v, 4));
      v = fmaxf(v, __shfl_xor(v, 8));
      float mn = fmaxf(m[i], v);
      al[i] = __expf(0.125f * (m[i] - mn));
      m[i] = mn;
      ps[i] = 0.f;
    }
#pragma unroll
    for (int n = 0; n < 4; ++n)
#pragma unroll
      for (int i = 0; i < 4; ++i) {
        float p = __expf(0.125f * (s[n][i] - m[i]));
        ps[i] += p;
        int row = lg * 4 + i;
        int col = n * 16 + lr;
        *(unsigned short*)((char*)Ps + w * 2048 + row * 128 +
                           ((2 * col) ^ ((row & 7) << 4))) = f2b(p);
      }
#pragma unroll
    for (int i = 0; i < 4; ++i) {
      float v = ps[i];
      v += __shfl_xor(v, 1);
      v += __shfl_xor(v, 2);
      v += __shfl_xor(v, 4);
      v += __shfl_xor(v, 8);
      lsum[i] = lsum[i] * al[i] + v;
#pragma unroll
      for (int dd = 0; dd < 4; ++dd) o[dd][i] *= al[i];
    }
    asm volatile("s_waitcnt lgkmcnt(0)" ::: "memory");
    // PV: A = P (row=lr, k=keys), B = Vt rows (col=dim)
    short8 pa[2];
#pragma unroll
    for (int kk = 0; kk < 2; ++kk)
      pa[kk] = *(const short8*)((char*)Ps + w * 2048 + lr * 128 +
                                ((kk * 64 + lg * 16) ^ ((lr & 7) << 4)));
#pragma unroll
    for (int kk = 0; kk < 2; ++kk)
#pragma unroll
      for (int dd = 0; dd < 4; ++dd) {
        int d = dd * 16 + lr;
        short8 vb = *(const short8*)((char*)Vs + d * 128 +
                                     ((kk * 64 + lg * 16) ^ ((d & 7) << 4)));
        o[dd] = __builtin_amdgcn_mfma_f32_16x16x32_bf16(pa[kk], vb, o[dd], 0, 0, 0);
      }
    __syncthreads();
  }

  // finalize: out[b][s][h*64+d]
#pragma unroll
  for (int i = 0; i < 4; ++i) {
    float inv = 1.f / lsum[i];
    int srow = qt * 64 + w * 16 + lg * 4 + i;
    unsigned short* orow = AttnC + (size_t)((bh >> 4) * S_ + srow) * DM + (bh & 15) * HD;
#pragma unroll
    for (int dd = 0; dd < 4; ++dd)
      orow[dd * 16 + lr] = f2b(o[dd][i] * inv);
  }
}

extern "C" void kernel_launch(void* const* d_in, const int* in_sizes, int n_in,
                              void* d_out, int out_size, void* d_ws, size_t ws_size,
                              hipStream_t stream) {
  const float* x = (const float*)d_in[0];
  const float* wq = (const float*)d_in[2];
  const float* bq = (const float*)d_in[3];
  const float* wk = (const float*)d_in[4];
  const float* bk = (const float*)d_in[5];
  const float* wv = (const float*)d_in[6];
  const float* bv = (const float*)d_in[7];
  const float* wo = (const float*)d_in[8];
  const float* bo = (const float*)d_in[9];

  char* ws = (char*)d_ws;
  const size_t MB = 1024ull * 1024ull;
  unsigned short* Xc = (unsigned short*)(ws);            // 8 MB
  unsigned short* Wt = (unsigned short*)(ws + 8 * MB);   // 4 x 2 MB
  unsigned short* Qb = (unsigned short*)(ws + 16 * MB);  // 8 MB
  unsigned short* Kb = (unsigned short*)(ws + 24 * MB);  // 8 MB
  unsigned short* Vb = (unsigned short*)(ws + 32 * MB);  // 8 MB
  unsigned short* Ac = (unsigned short*)(ws + 40 * MB);  // 8 MB

  cast_kernel<<<4096, 256, 0, stream>>>(x, Xc, 2 * S_ * DM);
  trans_kernel<<<dim3(32, 32, 4), 256, 0, stream>>>(wq, wk, wv, wo, Wt);
  gemm_kernel<<<dim3(32, 8), 256, 0, stream>>>(Xc, Wt + 0ull * DM * DM, bq, Qb, 0);
  gemm_kernel<<<dim3(32, 8), 256, 0, stream>>>(Xc, Wt + 1ull * DM * DM, bk, Kb, 1);
  gemm_kernel<<<dim3(32, 8), 256, 0, stream>>>(Xc, Wt + 2ull * DM * DM, bv, Vb, 2);
  attn_kernel<<<dim3(32, 32), 256, 0, stream>>>(Qb, Kb, Vb, Ac);
  gemm_kernel<<<dim3(32, 8), 256, 0, stream>>>(Ac, Wt + 3ull * DM * DM, bo, (float*)d_out, 3);
}

// Round 3
// 151.497 us; speedup vs baseline: 16.6163x; 1.3420x over previous
//
#include <hip/hip_runtime.h>
#include <hip/hip_bf16.h>

// B=2, S=2048, D=1024, H=16, HD=64. Causal MHA + RoPE.
// cast -> trans -> rope_tab -> fused QKV GEMM (RoPE + 1/8 Q-scale fused)
//   -> MFMA flash attn (double-buffered, conflict-free staging) -> out GEMM.
// ws: Xc 8MB | Wt 8MB | QKV 24MB | Ac 8MB | rope_tab 0.5MB

#define S_ 2048
#define DM 1024
#define HD 64

typedef __attribute__((ext_vector_type(8))) short short8;   // 8 bf16
typedef __attribute__((ext_vector_type(4))) float floatx4;  // 4 f32

__device__ __forceinline__ unsigned short f2b(float x) {
  union { __hip_bfloat16 h; unsigned short u; } cv;
  cv.h = __float2bfloat16(x);
  return cv.u;
}

__device__ __forceinline__ void gload_lds16(const unsigned short* g, unsigned short* l) {
  typedef const __attribute__((address_space(1))) unsigned int* gp_t;
  typedef __attribute__((address_space(3))) unsigned int* lp_t;
  __builtin_amdgcn_global_load_lds((gp_t)(const void*)g, (lp_t)(void*)l, 16, 0, 0);
}

// ---------------- cast x f32 -> bf16 ----------------
__global__ void cast_kernel(const float* __restrict__ in,
                            unsigned short* __restrict__ out, int n) {
  int i = (blockIdx.x * blockDim.x + threadIdx.x) * 4;
  if (i >= n) return;
  float4 v = *(const float4*)(in + i);
  ushort4 o;
  o.x = f2b(v.x); o.y = f2b(v.y); o.z = f2b(v.z); o.w = f2b(v.w);
  *(ushort4*)(out + i) = o;
}

// ---------------- transpose + cast weights: Wt[n][k] = W[k][n] ----------------
__global__ void trans_kernel(const float* __restrict__ w0, const float* __restrict__ w1,
                             const float* __restrict__ w2, const float* __restrict__ w3,
                             unsigned short* __restrict__ wt) {
  __shared__ float tile[32][33];
  const float* W = (blockIdx.z == 0) ? w0 : (blockIdx.z == 1) ? w1
                   : (blockIdx.z == 2) ? w2 : w3;
  unsigned short* Wt = wt + (size_t)blockIdx.z * DM * DM;
  const int tx = threadIdx.x & 31;
  const int ty = threadIdx.x >> 5;
  const int k0 = blockIdx.x * 32;
  const int c0 = blockIdx.y * 32;
#pragma unroll
  for (int i = 0; i < 4; ++i)
    tile[ty + i * 8][tx] = W[(size_t)(k0 + ty + i * 8) * DM + c0 + tx];
  __syncthreads();
#pragma unroll
  for (int i = 0; i < 4; ++i)
    Wt[(size_t)(c0 + ty + i * 8) * DM + k0 + tx] = f2b(tile[tx][ty + i * 8]);
}

// ---------------- RoPE table: tab[s][d2] = (cos, sin), d2 = d>>1 ----------------
__global__ void rope_kernel(float2* __restrict__ tab) {
  int i = blockIdx.x * 256 + threadIdx.x;  // 65536 = 2048*32
  int s = i >> 5, d2 = i & 31;
  float th = expf(-(float)d2 * (9.210340371976184f / 32.0f));
  float sn, cs;
  sincosf((float)s * th, &sn, &cs);
  tab[i] = make_float2(cs, sn);
}

// ---------------- fused QKV GEMM: A[4096][1024] x Wt_qkv[3072][1024]^T ----------------
// grid (32, 24). mat = by>>3: 0=Q (RoPE+1/8), 1=K (RoPE), 2=V. bf16 out [mat][bh][s][d].
__global__ __launch_bounds__(256, 3) void gemm_qkv(
    const unsigned short* __restrict__ A, const unsigned short* __restrict__ Wt,
    const float* __restrict__ bq, const float* __restrict__ bk,
    const float* __restrict__ bv, const float2* __restrict__ rope,
    unsigned short* __restrict__ QKV) {
  __shared__ __attribute__((aligned(16))) unsigned short As[128 * 32];
  __shared__ __attribute__((aligned(16))) unsigned short Bs[128 * 32];
  const int r0 = blockIdx.x * 128;
  const int c0 = blockIdx.y * 128;
  const int t = threadIdx.x;
  const int lane = t & 63;
  const int wv = t >> 6;
  const int wr = (wv >> 1) * 64;
  const int wc = (wv & 1) * 64;
  const int lr = lane & 15;
  const int lg = lane >> 4;

  const int srow = wv * 32 + (lane >> 2);
  const int sseg = (lane & 3) * 8;
  const unsigned short* Ag = A + (size_t)(r0 + srow) * DM + sseg;
  const unsigned short* Bg = Wt + (size_t)(c0 + srow) * DM + sseg;
  unsigned short* lA = &As[wv * 1024];
  unsigned short* lB = &Bs[wv * 1024];

  floatx4 acc[4][4] = {};

  for (int k0 = 0; k0 < DM; k0 += 32) {
    gload_lds16(Ag + k0, lA);
    gload_lds16(Ag + k0 + 16 * DM, lA + 512);
    gload_lds16(Bg + k0, lB);
    gload_lds16(Bg + k0 + 16 * DM, lB + 512);
    __syncthreads();
    short8 af[4], bf[4];
#pragma unroll
    for (int m = 0; m < 4; ++m)
      af[m] = *(const short8*)(&As[(wr + m * 16 + lr) * 32 + lg * 8]);
#pragma unroll
    for (int n = 0; n < 4; ++n)
      bf[n] = *(const short8*)(&Bs[(wc + n * 16 + lr) * 32 + lg * 8]);
#pragma unroll
    for (int m = 0; m < 4; ++m)
#pragma unroll
      for (int n = 0; n < 4; ++n)
        acc[m][n] = __builtin_amdgcn_mfma_f32_16x16x32_bf16(af[m], bf[n], acc[m][n], 0, 0, 0);
    __syncthreads();
  }

  const int mat = blockIdx.y >> 3;
  const float* bias = (mat == 0) ? bq : (mat == 1) ? bk : bv;
  const int rbase = r0 + wr + lg * 4;
  const int cbase = c0 + wc + lr;
#pragma unroll
  for (int n = 0; n < 4; ++n) {
    const int c = cbase + n * 16;
    const int cc = c & (DM - 1);
    const float bvv = bias[cc];
    const int d = c & 63;
    const int h = cc >> 6;
#pragma unroll
    for (int m = 0; m < 4; ++m) {
#pragma unroll
      for (int i = 0; i < 4; ++i) {
        const int r = rbase + m * 16 + i;
        const int s = r & (S_ - 1);
        const int b = r >> 11;
        float v = acc[m][n][i] + bvv;
        float pv = __shfl_xor(v, 1);
        if (mat < 2) {
          float2 cssn = rope[s * 32 + (d >> 1)];
          v = (d & 1) ? fmaf(v, cssn.x, pv * cssn.y) : fmaf(v, cssn.x, -pv * cssn.y);
          if (mat == 0) v *= 0.125f;
        }
        QKV[((size_t)((mat << 5) | (b << 4) | h) * S_ + s) * HD + d] = f2b(v);
      }
    }
  }
}

// ---------------- out projection GEMM: Ac[4096][1024] x Wo^T -> f32 ----------------
__global__ __launch_bounds__(256, 3) void gemm_out(
    const unsigned short* __restrict__ A, const unsigned short* __restrict__ Wt,
    const float* __restrict__ bias, float* __restrict__ out) {
  __shared__ __attribute__((aligned(16))) unsigned short As[128 * 32];
  __shared__ __attribute__((aligned(16))) unsigned short Bs[128 * 32];
  const int r0 = blockIdx.x * 128;
  const int c0 = blockIdx.y * 128;
  const int t = threadIdx.x;
  const int lane = t & 63;
  const int wv = t >> 6;
  const int wr = (wv >> 1) * 64;
  const int wc = (wv & 1) * 64;
  const int lr = lane & 15;
  const int lg = lane >> 4;

  const int srow = wv * 32 + (lane >> 2);
  const int sseg = (lane & 3) * 8;
  const unsigned short* Ag = A + (size_t)(r0 + srow) * DM + sseg;
  const unsigned short* Bg = Wt + (size_t)(c0 + srow) * DM + sseg;
  unsigned short* lA = &As[wv * 1024];
  unsigned short* lB = &Bs[wv * 1024];

  floatx4 acc[4][4] = {};

  for (int k0 = 0; k0 < DM; k0 += 32) {
    gload_lds16(Ag + k0, lA);
    gload_lds16(Ag + k0 + 16 * DM, lA + 512);
    gload_lds16(Bg + k0, lB);
    gload_lds16(Bg + k0 + 16 * DM, lB + 512);
    __syncthreads();
    short8 af[4], bf[4];
#pragma unroll
    for (int m = 0; m < 4; ++m)
      af[m] = *(const short8*)(&As[(wr + m * 16 + lr) * 32 + lg * 8]);
#pragma unroll
    for (int n = 0; n < 4; ++n)
      bf[n] = *(const short8*)(&Bs[(wc + n * 16 + lr) * 32 + lg * 8]);
#pragma unroll
    for (int m = 0; m < 4; ++m)
#pragma unroll
      for (int n = 0; n < 4; ++n)
        acc[m][n] = __builtin_amdgcn_mfma_f32_16x16x32_bf16(af[m], bf[n], acc[m][n], 0, 0, 0);
    __syncthreads();
  }

  const int rbase = r0 + wr + lg * 4;
  const int cbase = c0 + wc + lr;
#pragma unroll
  for (int n = 0; n < 4; ++n) {
    const int c = cbase + n * 16;
    const float bvv = bias[c];
#pragma unroll
    for (int m = 0; m < 4; ++m) {
#pragma unroll
      for (int i = 0; i < 4; ++i) {
        const int r = rbase + m * 16 + i;
        out[(size_t)r * DM + c] = acc[m][n][i] + bvv;
      }
    }
  }
}

// ---------------- MFMA flash attention (double-buffered) ----------------
// grid (bh=32, 32 q-tiles reversed), 256 thr = 4 waves; wave w owns q rows
// [qt*64 + w*16, +16). Q pre-scaled by 1/8. One barrier per key-tile.
__global__ __launch_bounds__(256, 4) void attn_kernel(
    const unsigned short* __restrict__ Q, const unsigned short* __restrict__ K,
    const unsigned short* __restrict__ V, unsigned short* __restrict__ AttnC) {
  __shared__ __attribute__((aligned(16))) unsigned short Ks[2][64 * 64];
  __shared__ __attribute__((aligned(16))) unsigned short Vs[2][64 * 64];
  __shared__ __attribute__((aligned(16))) unsigned short Ps[4][16 * 64];

  const int bh = blockIdx.x;
  const int qt = (int)(gridDim.y - 1) - (int)blockIdx.y;  // big blocks first
  const int tid = threadIdx.x;
  const int w = tid >> 6;
  const int l = tid & 63;
  const int lg = l >> 4;   // 0..3
  const int lr = l & 15;
  const size_t base = (size_t)bh * S_ * HD;

  // Q A-frags (row = lr, k = kk*32 + lg*8 + j)
  short8 qf[2];
  {
    const unsigned short* Qrow = Q + base + (size_t)(qt * 64 + w * 16 + lr) * HD + lg * 8;
    qf[0] = *(const short8*)(Qrow);
    qf[1] = *(const short8*)(Qrow + 32);
  }

  floatx4 o[4] = {};
  float m[4], lsum[4];
#pragma unroll
  for (int i = 0; i < 4; ++i) { m[i] = -1e30f; lsum[i] = 0.f; }

  // staging roles
  const int krow = tid >> 3;  // 0..31 (K rows krow, krow+32)
  const int kseg = tid & 7;
  const int oct = tid >> 5;   // 0..7  (V dims oct*8..+8)
  const int kp = tid & 31;    // key-pair 2kp, 2kp+1

  // prologue: load tile 0 into regs
  int4 kr0, kr1; short8 va, vb;
  {
    const unsigned short* Kg = K + base;
    const unsigned short* Vg = V + base;
    kr0 = *(const int4*)(Kg + krow * 64 + kseg * 8);
    kr1 = *(const int4*)(Kg + (krow + 32) * 64 + kseg * 8);
    va = *(const short8*)(Vg + (2 * kp) * 64 + oct * 8);
    vb = *(const short8*)(Vg + (2 * kp + 1) * 64 + oct * 8);
  }

  for (int t = 0; t <= qt; ++t) {
    const int cur = t & 1;
    // (a) write regs (tile t) -> LDS[cur]; conflict-free phases
    {
      char* Kb = (char*)Ks[cur];
      *(int4*)(Kb + krow * 128 + ((kseg * 16) ^ ((krow & 7) << 4))) = kr0;
      *(int4*)(Kb + (krow + 32) * 128 + ((kseg * 16) ^ ((krow & 7) << 4))) = kr1;
      char* Vb = (char*)Vs[cur];
#pragma unroll
      for (int j = 0; j < 8; ++j) {
        int d = oct * 8 + j;  // d&7 == j
        unsigned int pk = (unsigned int)(unsigned short)va[j] |
                          ((unsigned int)(unsigned short)vb[j] << 16);
        *(unsigned int*)(Vb + d * 128 + ((4 * kp) ^ (j << 4))) = pk;
      }
    }
    // (b) issue loads for tile t+1
    if (t < qt) {
      const unsigned short* Kg = K + base + (size_t)(t + 1) * 64 * HD;
      const unsigned short* Vg = V + base + (size_t)(t + 1) * 64 * HD;
      kr0 = *(const int4*)(Kg + krow * 64 + kseg * 8);
      kr1 = *(const int4*)(Kg + (krow + 32) * 64 + kseg * 8);
      va = *(const short8*)(Vg + (2 * kp) * 64 + oct * 8);
      vb = *(const short8*)(Vg + (2 * kp + 1) * 64 + oct * 8);
    }
    // (c) one barrier
    __syncthreads();

    // (d) compute on LDS[cur]
    floatx4 s[4] = {};
    __builtin_amdgcn_s_setprio(1);
#pragma unroll
    for (int kk = 0; kk < 2; ++kk) {
#pragma unroll
      for (int n = 0; n < 4; ++n) {
        int c = n * 16 + lr;
        short8 kb = *(const short8*)((char*)Ks[cur] + c * 128 +
                                     ((kk * 64 + lg * 16) ^ ((c & 7) << 4)));
        s[n] = __builtin_amdgcn_mfma_f32_16x16x32_bf16(qf[kk], kb, s[n], 0, 0, 0);
      }
    }
    __builtin_amdgcn_s_setprio(0);
    if (t == qt) {
#pragma unroll
      for (int n = 0; n < 4; ++n)
#pragma unroll
        for (int i = 0; i < 4; ++i)
          if (n * 16 + lr > w * 16 + lg * 4 + i) s[n][i] = -1e30f;
    }

    // online softmax (row = lg*4+i; reduce across 16-lane col group)
    float al[4], ps[4];
#pragma unroll
    for (int i = 0; i < 4; ++i) {
      float v = fmaxf(fmaxf(s[0][i], s[1][i]), fmaxf(s[2][i], s[3][i]));
      v = fmaxf(v, __shfl_xor(v, 1));
      v = fmaxf(v, __shfl_xor(v, 2));
      v = fmaxf(v, __shfl_xor(v, 4));
      v = fmaxf(v, __shfl_xor(v, 8));
      float mn = fmaxf(m[i], v);
      al[i] = __expf(m[i] - mn);
      m[i] = mn;
      ps[i] = 0.f;
    }
#pragma unroll
    for (int n = 0; n < 4; ++n)
#pragma unroll
      for (int i = 0; i < 4; ++i) {
        float p = __expf(s[n][i] - m[i]);
        ps[i] += p;
        int row = lg * 4 + i;
        int col = n * 16 + lr;
        *(unsigned short*)((char*)Ps[w] + row * 128 +
                           ((2 * col) ^ ((row & 7) << 4))) = f2b(p);
      }
#pragma unroll
    for (int i = 0; i < 4; ++i) {
      float v = ps[i];
      v += __shfl_xor(v, 1);
      v += __shfl_xor(v, 2);
      v += __shfl_xor(v, 4);
      v += __shfl_xor(v, 8);
      lsum[i] = lsum[i] * al[i] + v;
#pragma unroll
      for (int dd = 0; dd < 4; ++dd) o[dd][i] *= al[i];
    }
    // PV
    short8 pa[2];
#pragma unroll
    for (int kk = 0; kk < 2; ++kk)
      pa[kk] = *(const short8*)((char*)Ps[w] + lr * 128 +
                                ((kk * 64 + lg * 16) ^ ((lr & 7) << 4)));
    __builtin_amdgcn_s_setprio(1);
#pragma unroll
    for (int kk = 0; kk < 2; ++kk)
#pragma unroll
      for (int dd = 0; dd < 4; ++dd) {
        int d = dd * 16 + lr;
        short8 vbf = *(const short8*)((char*)Vs[cur] + d * 128 +
                                      ((kk * 64 + lg * 16) ^ ((d & 7) << 4)));
        o[dd] = __builtin_amdgcn_mfma_f32_16x16x32_bf16(pa[kk], vbf, o[dd], 0, 0, 0);
      }
    __builtin_amdgcn_s_setprio(0);
  }

  // finalize: out[b][s][h*64+d]
#pragma unroll
  for (int i = 0; i < 4; ++i) {
    float inv = 1.f / lsum[i];
    int srow = qt * 64 + w * 16 + lg * 4 + i;
    unsigned short* orow = AttnC + (size_t)((bh >> 4) * S_ + srow) * DM + (bh & 15) * HD;
#pragma unroll
    for (int dd = 0; dd < 4; ++dd)
      orow[dd * 16 + lr] = f2b(o[dd][i] * inv);
  }
}

extern "C" void kernel_launch(void* const* d_in, const int* in_sizes, int n_in,
                              void* d_out, int out_size, void* d_ws, size_t ws_size,
                              hipStream_t stream) {
  const float* x = (const float*)d_in[0];
  const float* wq = (const float*)d_in[2];
  const float* bq = (const float*)d_in[3];
  const float* wk = (const float*)d_in[4];
  const float* bk = (const float*)d_in[5];
  const float* wv = (const float*)d_in[6];
  const float* bv = (const float*)d_in[7];
  const float* wo = (const float*)d_in[8];
  const float* bo = (const float*)d_in[9];

  char* ws = (char*)d_ws;
  const size_t MB = 1024ull * 1024ull;
  unsigned short* Xc = (unsigned short*)(ws);             // 8 MB
  unsigned short* Wt = (unsigned short*)(ws + 8 * MB);    // 4 x 2 MB
  unsigned short* QKVb = (unsigned short*)(ws + 16 * MB); // 24 MB
  unsigned short* Ac = (unsigned short*)(ws + 40 * MB);   // 8 MB
  float2* rope = (float2*)(ws + 48 * MB);                 // 0.5 MB

  cast_kernel<<<4096, 256, 0, stream>>>(x, Xc, 2 * S_ * DM);
  trans_kernel<<<dim3(32, 32, 4), 256, 0, stream>>>(wq, wk, wv, wo, Wt);
  rope_kernel<<<256, 256, 0, stream>>>(rope);
  gemm_qkv<<<dim3(32, 24), 256, 0, stream>>>(Xc, Wt, bq, bk, bv, rope, QKVb);
  attn_kernel<<<dim3(32, 32), 256, 0, stream>>>(
      QKVb, QKVb + 32ull * S_ * HD, QKVb + 64ull * S_ * HD, Ac);
  gemm_out<<<dim3(32, 8), 256, 0, stream>>>(Ac, Wt + 3ull * DM * DM, bo, (float*)d_out);
}

// Round 4
// 127.598 us; speedup vs baseline: 19.7285x; 1.1873x over previous
//
#include <hip/hip_runtime.h>
#include <hip/hip_bf16.h>

// B=2, S=2048, D=1024, H=16, HD=64. Causal MHA + RoPE.
// cast -> trans -> rope_tab -> fused QKV GEMM (RoPE + 0.125*log2e Q-scale fused)
//   -> MFMA flash attn (swapped QK^T, lane-local softmax, exp2) -> out GEMM.
// ws: Xc 8MB | Wt 8MB | QKV 24MB | Ac 8MB | rope_tab 0.5MB

#define S_ 2048
#define DM 1024
#define HD 64

typedef __attribute__((ext_vector_type(8))) short short8;   // 8 bf16
typedef __attribute__((ext_vector_type(4))) float floatx4;  // 4 f32

__device__ __forceinline__ unsigned short f2b(float x) {
  union { __hip_bfloat16 h; unsigned short u; } cv;
  cv.h = __float2bfloat16(x);
  return cv.u;
}

__device__ __forceinline__ void gload_lds16(const unsigned short* g, unsigned short* l) {
  typedef const __attribute__((address_space(1))) unsigned int* gp_t;
  typedef __attribute__((address_space(3))) unsigned int* lp_t;
  __builtin_amdgcn_global_load_lds((gp_t)(const void*)g, (lp_t)(void*)l, 16, 0, 0);
}

// ---------------- cast x f32 -> bf16 ----------------
__global__ void cast_kernel(const float* __restrict__ in,
                            unsigned short* __restrict__ out, int n) {
  int i = (blockIdx.x * blockDim.x + threadIdx.x) * 4;
  if (i >= n) return;
  float4 v = *(const float4*)(in + i);
  ushort4 o;
  o.x = f2b(v.x); o.y = f2b(v.y); o.z = f2b(v.z); o.w = f2b(v.w);
  *(ushort4*)(out + i) = o;
}

// ---------------- transpose + cast weights: Wt[n][k] = W[k][n] ----------------
__global__ void trans_kernel(const float* __restrict__ w0, const float* __restrict__ w1,
                             const float* __restrict__ w2, const float* __restrict__ w3,
                             unsigned short* __restrict__ wt) {
  __shared__ float tile[32][33];
  const float* W = (blockIdx.z == 0) ? w0 : (blockIdx.z == 1) ? w1
                   : (blockIdx.z == 2) ? w2 : w3;
  unsigned short* Wt = wt + (size_t)blockIdx.z * DM * DM;
  const int tx = threadIdx.x & 31;
  const int ty = threadIdx.x >> 5;
  const int k0 = blockIdx.x * 32;
  const int c0 = blockIdx.y * 32;
#pragma unroll
  for (int i = 0; i < 4; ++i)
    tile[ty + i * 8][tx] = W[(size_t)(k0 + ty + i * 8) * DM + c0 + tx];
  __syncthreads();
#pragma unroll
  for (int i = 0; i < 4; ++i)
    Wt[(size_t)(c0 + ty + i * 8) * DM + k0 + tx] = f2b(tile[tx][ty + i * 8]);
}

// ---------------- RoPE table: tab[s][d2] = (cos, sin), d2 = d>>1 ----------------
__global__ void rope_kernel(float2* __restrict__ tab) {
  int i = blockIdx.x * 256 + threadIdx.x;  // 65536 = 2048*32
  int s = i >> 5, d2 = i & 31;
  float th = expf(-(float)d2 * (9.210340371976184f / 32.0f));
  float sn, cs;
  sincosf((float)s * th, &sn, &cs);
  tab[i] = make_float2(cs, sn);
}

// ---------------- fused QKV GEMM: A[4096][1024] x Wt_qkv[3072][1024]^T ----------------
// grid (32, 24). mat = by>>3: 0=Q (RoPE + 0.125*log2e), 1=K (RoPE), 2=V.
__global__ __launch_bounds__(256, 3) void gemm_qkv(
    const unsigned short* __restrict__ A, const unsigned short* __restrict__ Wt,
    const float* __restrict__ bq, const float* __restrict__ bk,
    const float* __restrict__ bv, const float2* __restrict__ rope,
    unsigned short* __restrict__ QKV) {
  __shared__ __attribute__((aligned(16))) unsigned short As[128 * 32];
  __shared__ __attribute__((aligned(16))) unsigned short Bs[128 * 32];
  const int r0 = blockIdx.x * 128;
  const int c0 = blockIdx.y * 128;
  const int t = threadIdx.x;
  const int lane = t & 63;
  const int wv = t >> 6;
  const int wr = (wv >> 1) * 64;
  const int wc = (wv & 1) * 64;
  const int lr = lane & 15;
  const int lg = lane >> 4;

  const int srow = wv * 32 + (lane >> 2);
  const int sseg = (lane & 3) * 8;
  const unsigned short* Ag = A + (size_t)(r0 + srow) * DM + sseg;
  const unsigned short* Bg = Wt + (size_t)(c0 + srow) * DM + sseg;
  unsigned short* lA = &As[wv * 1024];
  unsigned short* lB = &Bs[wv * 1024];

  floatx4 acc[4][4] = {};

  for (int k0 = 0; k0 < DM; k0 += 32) {
    gload_lds16(Ag + k0, lA);
    gload_lds16(Ag + k0 + 16 * DM, lA + 512);
    gload_lds16(Bg + k0, lB);
    gload_lds16(Bg + k0 + 16 * DM, lB + 512);
    __syncthreads();
    short8 af[4], bf[4];
#pragma unroll
    for (int m = 0; m < 4; ++m)
      af[m] = *(const short8*)(&As[(wr + m * 16 + lr) * 32 + lg * 8]);
#pragma unroll
    for (int n = 0; n < 4; ++n)
      bf[n] = *(const short8*)(&Bs[(wc + n * 16 + lr) * 32 + lg * 8]);
#pragma unroll
    for (int m = 0; m < 4; ++m)
#pragma unroll
      for (int n = 0; n < 4; ++n)
        acc[m][n] = __builtin_amdgcn_mfma_f32_16x16x32_bf16(af[m], bf[n], acc[m][n], 0, 0, 0);
    __syncthreads();
  }

  const int mat = blockIdx.y >> 3;
  const float* bias = (mat == 0) ? bq : (mat == 1) ? bk : bv;
  const int rbase = r0 + wr + lg * 4;
  const int cbase = c0 + wc + lr;
#pragma unroll
  for (int n = 0; n < 4; ++n) {
    const int c = cbase + n * 16;
    const int cc = c & (DM - 1);
    const float bvv = bias[cc];
    const int d = c & 63;
    const int h = cc >> 6;
#pragma unroll
    for (int m = 0; m < 4; ++m) {
#pragma unroll
      for (int i = 0; i < 4; ++i) {
        const int r = rbase + m * 16 + i;
        const int s = r & (S_ - 1);
        const int b = r >> 11;
        float v = acc[m][n][i] + bvv;
        float pv = __shfl_xor(v, 1);
        if (mat < 2) {
          float2 cssn = rope[s * 32 + (d >> 1)];
          v = (d & 1) ? fmaf(v, cssn.x, pv * cssn.y) : fmaf(v, cssn.x, -pv * cssn.y);
          if (mat == 0) v *= 0.18033688011112042f;  // 0.125 * log2(e)
        }
        QKV[((size_t)((mat << 5) | (b << 4) | h) * S_ + s) * HD + d] = f2b(v);
      }
    }
  }
}

// ---------------- out projection GEMM: Ac[4096][1024] x Wo^T -> f32 ----------------
__global__ __launch_bounds__(256, 3) void gemm_out(
    const unsigned short* __restrict__ A, const unsigned short* __restrict__ Wt,
    const float* __restrict__ bias, float* __restrict__ out) {
  __shared__ __attribute__((aligned(16))) unsigned short As[128 * 32];
  __shared__ __attribute__((aligned(16))) unsigned short Bs[128 * 32];
  const int r0 = blockIdx.x * 128;
  const int c0 = blockIdx.y * 128;
  const int t = threadIdx.x;
  const int lane = t & 63;
  const int wv = t >> 6;
  const int wr = (wv >> 1) * 64;
  const int wc = (wv & 1) * 64;
  const int lr = lane & 15;
  const int lg = lane >> 4;

  const int srow = wv * 32 + (lane >> 2);
  const int sseg = (lane & 3) * 8;
  const unsigned short* Ag = A + (size_t)(r0 + srow) * DM + sseg;
  const unsigned short* Bg = Wt + (size_t)(c0 + srow) * DM + sseg;
  unsigned short* lA = &As[wv * 1024];
  unsigned short* lB = &Bs[wv * 1024];

  floatx4 acc[4][4] = {};

  for (int k0 = 0; k0 < DM; k0 += 32) {
    gload_lds16(Ag + k0, lA);
    gload_lds16(Ag + k0 + 16 * DM, lA + 512);
    gload_lds16(Bg + k0, lB);
    gload_lds16(Bg + k0 + 16 * DM, lB + 512);
    __syncthreads();
    short8 af[4], bf[4];
#pragma unroll
    for (int m = 0; m < 4; ++m)
      af[m] = *(const short8*)(&As[(wr + m * 16 + lr) * 32 + lg * 8]);
#pragma unroll
    for (int n = 0; n < 4; ++n)
      bf[n] = *(const short8*)(&Bs[(wc + n * 16 + lr) * 32 + lg * 8]);
#pragma unroll
    for (int m = 0; m < 4; ++m)
#pragma unroll
      for (int n = 0; n < 4; ++n)
        acc[m][n] = __builtin_amdgcn_mfma_f32_16x16x32_bf16(af[m], bf[n], acc[m][n], 0, 0, 0);
    __syncthreads();
  }

  const int rbase = r0 + wr + lg * 4;
  const int cbase = c0 + wc + lr;
#pragma unroll
  for (int n = 0; n < 4; ++n) {
    const int c = cbase + n * 16;
    const float bvv = bias[c];
#pragma unroll
    for (int m = 0; m < 4; ++m) {
#pragma unroll
      for (int i = 0; i < 4; ++i) {
        const int r = rbase + m * 16 + i;
        out[(size_t)r * DM + c] = acc[m][n][i] + bvv;
      }
    }
  }
}

// ---------------- MFMA flash attention v2: swapped QK^T, lane-local softmax ----------------
// grid (bh=32, 32 q-tiles reversed), 256 thr = 4 waves; wave w owns q rows
// [qt*64 + w*16, +16), q = lane&15. Q pre-scaled by 0.125*log2e; exp2 softmax.
// S^T = mfma(K_frag, Q_frag): lane holds S[k = n*16+lg*4+i][q=lr].
// O^T = mfma(Vt_frag, Pt_frag): o[dd][i] = O[q=lr][d = dd*16+lg*4+i].
__global__ __launch_bounds__(256, 4) void attn_kernel(
    const unsigned short* __restrict__ Q, const unsigned short* __restrict__ K,
    const unsigned short* __restrict__ V, unsigned short* __restrict__ AttnC) {
  __shared__ __attribute__((aligned(16))) unsigned short Ks[2][64 * 64];
  __shared__ __attribute__((aligned(16))) unsigned short Vs[2][64 * 64];
  __shared__ __attribute__((aligned(16))) unsigned short Ps[4][16 * 64];

  const int bh = blockIdx.x;
  const int qt = (int)(gridDim.y - 1) - (int)blockIdx.y;  // big blocks first
  const int tid = threadIdx.x;
  const int w = tid >> 6;
  const int l = tid & 63;
  const int lg = l >> 4;   // 0..3
  const int lr = l & 15;   // q-row within wave tile
  const size_t base = (size_t)bh * S_ * HD;

  // Q as B-frag: B[k][q=lr] = Q[q][k], k = kk*32 + lg*8 + j
  short8 qf[2];
  {
    const unsigned short* Qrow = Q + base + (size_t)(qt * 64 + w * 16 + lr) * HD + lg * 8;
    qf[0] = *(const short8*)(Qrow);
    qf[1] = *(const short8*)(Qrow + 32);
  }

  floatx4 o[4] = {};
  float m = -1e30f, lsum = 0.f;  // per-lane: q = lr (lsum is lg-partial)

  // staging roles
  const int krow = tid >> 3;  // 0..31 (K rows krow, krow+32)
  const int kseg = tid & 7;
  const int oct = tid >> 5;   // 0..7  (V dims oct*8..+8)
  const int kp = tid & 31;    // key-pair 2kp, 2kp+1

  // prologue: load tile 0 into regs
  int4 kr0, kr1; short8 va, vb;
  {
    const unsigned short* Kg = K + base;
    const unsigned short* Vg = V + base;
    kr0 = *(const int4*)(Kg + krow * 64 + kseg * 8);
    kr1 = *(const int4*)(Kg + (krow + 32) * 64 + kseg * 8);
    va = *(const short8*)(Vg + (2 * kp) * 64 + oct * 8);
    vb = *(const short8*)(Vg + (2 * kp + 1) * 64 + oct * 8);
  }

  char* const Pw = (char*)Ps[w];
  const int pswz = (lr & 7) << 4;

  for (int t = 0; t <= qt; ++t) {
    const int cur = t & 1;
    // (a) write regs (tile t) -> LDS[cur]
    {
      char* Kb = (char*)Ks[cur];
      *(int4*)(Kb + krow * 128 + ((kseg * 16) ^ ((krow & 7) << 4))) = kr0;
      *(int4*)(Kb + (krow + 32) * 128 + ((kseg * 16) ^ ((krow & 7) << 4))) = kr1;
      char* Vb = (char*)Vs[cur];
#pragma unroll
      for (int j = 0; j < 8; ++j) {
        int d = oct * 8 + j;  // d&7 == j
        unsigned int pk = (unsigned int)(unsigned short)va[j] |
                          ((unsigned int)(unsigned short)vb[j] << 16);
        *(unsigned int*)(Vb + d * 128 + ((4 * kp) ^ (j << 4))) = pk;
      }
    }
    // (b) issue loads for tile t+1
    if (t < qt) {
      const unsigned short* Kg = K + base + (size_t)(t + 1) * 64 * HD;
      const unsigned short* Vg = V + base + (size_t)(t + 1) * 64 * HD;
      kr0 = *(const int4*)(Kg + krow * 64 + kseg * 8);
      kr1 = *(const int4*)(Kg + (krow + 32) * 64 + kseg * 8);
      va = *(const short8*)(Vg + (2 * kp) * 64 + oct * 8);
      vb = *(const short8*)(Vg + (2 * kp + 1) * 64 + oct * 8);
    }
    // (c) one barrier
    __syncthreads();

    // (d) S^T = K Q^T : s[n][i] = S[key = n*16+lg*4+i][q = lr]
    floatx4 s[4] = {};
    __builtin_amdgcn_s_setprio(1);
#pragma unroll
    for (int kk = 0; kk < 2; ++kk) {
#pragma unroll
      for (int n = 0; n < 4; ++n) {
        int r = n * 16 + lr;  // key row this lane reads for the A-frag
        short8 kf = *(const short8*)((char*)Ks[cur] + r * 128 +
                                     ((kk * 64 + lg * 16) ^ ((r & 7) << 4)));
        s[n] = __builtin_amdgcn_mfma_f32_16x16x32_bf16(kf, qf[kk], s[n], 0, 0, 0);
      }
    }
    __builtin_amdgcn_s_setprio(0);
    if (t == qt) {  // causal: key_in_tile > q_in_tile
#pragma unroll
      for (int n = 0; n < 4; ++n)
#pragma unroll
        for (int i = 0; i < 4; ++i)
          if (n * 16 + lg * 4 + i > w * 16 + lr) s[n][i] = -1e30f;
    }

    // lane-local softmax for q = lr (only max needs cross-lane: lanes lr, lr+16/32/48)
    float tm0 = fmaxf(fmaxf(s[0][0], s[0][1]), fmaxf(s[0][2], s[0][3]));
    float tm1 = fmaxf(fmaxf(s[1][0], s[1][1]), fmaxf(s[1][2], s[1][3]));
    float tm2 = fmaxf(fmaxf(s[2][0], s[2][1]), fmaxf(s[2][2], s[2][3]));
    float tm3 = fmaxf(fmaxf(s[3][0], s[3][1]), fmaxf(s[3][2], s[3][3]));
    float tm = fmaxf(fmaxf(tm0, tm1), fmaxf(tm2, tm3));
    tm = fmaxf(tm, __shfl_xor(tm, 16));
    tm = fmaxf(tm, __shfl_xor(tm, 32));
    const float mn = fmaxf(m, tm);
    const float al = exp2f(m - mn);
    m = mn;
    float ps = 0.f;
#pragma unroll
    for (int n = 0; n < 4; ++n) {
#pragma unroll
      for (int i = 0; i < 4; ++i) {
        float p = exp2f(s[n][i] - mn);
        s[n][i] = p;
        ps += p;
      }
    }
    lsum = lsum * al + ps;  // lg-partial; reduced once at the end
#pragma unroll
    for (int dd = 0; dd < 4; ++dd) o[dd] *= al;

    // write P^T rows into Ps[w]: row = q = lr, col k = n*16+lg*4+{0..3}
#pragma unroll
    for (int n = 0; n < 4; ++n) {
#pragma unroll
      for (int h = 0; h < 2; ++h) {
        unsigned int pk = (unsigned int)f2b(s[n][2 * h]) |
                          ((unsigned int)f2b(s[n][2 * h + 1]) << 16);
        *(unsigned int*)(Pw + lr * 128 + (((n * 16 + lg * 4 + 2 * h) * 2) ^ pswz)) = pk;
      }
    }
    // P^T as B-frag: B[k][q=lr], k = kk*32 + lg*8 + j
    short8 pb[2];
#pragma unroll
    for (int kk = 0; kk < 2; ++kk)
      pb[kk] = *(const short8*)(Pw + lr * 128 + ((kk * 64 + lg * 16) ^ pswz));
    // O^T += V^T P^T : A = Vt rows d = dd*16+lr
    __builtin_amdgcn_s_setprio(1);
#pragma unroll
    for (int kk = 0; kk < 2; ++kk)
#pragma unroll
      for (int dd = 0; dd < 4; ++dd) {
        int d = dd * 16 + lr;
        short8 vbf = *(const short8*)((char*)Vs[cur] + d * 128 +
                                      ((kk * 64 + lg * 16) ^ ((d & 7) << 4)));
        o[dd] = __builtin_amdgcn_mfma_f32_16x16x32_bf16(vbf, pb[kk], o[dd], 0, 0, 0);
      }
    __builtin_amdgcn_s_setprio(0);
  }

  // reduce lsum across the 4 lg-partials, then write O[q=lr][d=dd*16+lg*4+i]
  lsum += __shfl_xor(lsum, 16);
  lsum += __shfl_xor(lsum, 32);
  const float inv = 1.f / lsum;
  unsigned short* orow =
      AttnC + (size_t)((bh >> 4) * S_ + qt * 64 + w * 16 + lr) * DM + (bh & 15) * HD;
#pragma unroll
  for (int dd = 0; dd < 4; ++dd) {
    unsigned int w0 = (unsigned int)f2b(o[dd][0] * inv) |
                      ((unsigned int)f2b(o[dd][1] * inv) << 16);
    unsigned int w1 = (unsigned int)f2b(o[dd][2] * inv) |
                      ((unsigned int)f2b(o[dd][3] * inv) << 16);
    *(uint2*)(orow + dd * 16 + lg * 4) = make_uint2(w0, w1);
  }
}

extern "C" void kernel_launch(void* const* d_in, const int* in_sizes, int n_in,
                              void* d_out, int out_size, void* d_ws, size_t ws_size,
                              hipStream_t stream) {
  const float* x = (const float*)d_in[0];
  const float* wq = (const float*)d_in[2];
  const float* bq = (const float*)d_in[3];
  const float* wk = (const float*)d_in[4];
  const float* bk = (const float*)d_in[5];
  const float* wv = (const float*)d_in[6];
  const float* bv = (const float*)d_in[7];
  const float* wo = (const float*)d_in[8];
  const float* bo = (const float*)d_in[9];

  char* ws = (char*)d_ws;
  const size_t MB = 1024ull * 1024ull;
  unsigned short* Xc = (unsigned short*)(ws);             // 8 MB
  unsigned short* Wt = (unsigned short*)(ws + 8 * MB);    // 4 x 2 MB
  unsigned short* QKVb = (unsigned short*)(ws + 16 * MB); // 24 MB
  unsigned short* Ac = (unsigned short*)(ws + 40 * MB);   // 8 MB
  float2* rope = (float2*)(ws + 48 * MB);                 // 0.5 MB

  cast_kernel<<<4096, 256, 0, stream>>>(x, Xc, 2 * S_ * DM);
  trans_kernel<<<dim3(32, 32, 4), 256, 0, stream>>>(wq, wk, wv, wo, Wt);
  rope_kernel<<<256, 256, 0, stream>>>(rope);
  gemm_qkv<<<dim3(32, 24), 256, 0, stream>>>(Xc, Wt, bq, bk, bv, rope, QKVb);
  attn_kernel<<<dim3(32, 32), 256, 0, stream>>>(
      QKVb, QKVb + 32ull * S_ * HD, QKVb + 64ull * S_ * HD, Ac);
  gemm_out<<<dim3(32, 8), 256, 0, stream>>>(Ac, Wt + 3ull * DM * DM, bo, (float*)d_out);
}

// Round 5
// 120.479 us; speedup vs baseline: 20.8942x; 1.0591x over previous
//
#include <hip/hip_runtime.h>
#include <hip/hip_bf16.h>

// B=2, S=2048, D=1024, H=16, HD=64. Causal MHA + RoPE.
// cast -> trans -> rope_tab -> fused QKV GEMM (BK=64, swizzled; RoPE fused)
//   -> MFMA flash attn (QBLK=128, 8 waves, swapped QK^T, lane-local softmax,
//      defer-max) -> out GEMM (BK=64).
// ws: Xc 8MB | Wt 8MB | QKV 24MB | Ac 8MB | rope_tab 0.5MB

#define S_ 2048
#define DM 1024
#define HD 64

typedef __attribute__((ext_vector_type(8))) short short8;   // 8 bf16
typedef __attribute__((ext_vector_type(4))) short short4v;  // 4 bf16
typedef __attribute__((ext_vector_type(4))) float floatx4;  // 4 f32

__device__ __forceinline__ unsigned short f2b(float x) {
  union { __hip_bfloat16 h; unsigned short u; } cv;
  cv.h = __float2bfloat16(x);
  return cv.u;
}

__device__ __forceinline__ void gload_lds16(const unsigned short* g, unsigned short* l) {
  typedef const __attribute__((address_space(1))) unsigned int* gp_t;
  typedef __attribute__((address_space(3))) unsigned int* lp_t;
  __builtin_amdgcn_global_load_lds((gp_t)(const void*)g, (lp_t)(void*)l, 16, 0, 0);
}

// ---------------- cast x f32 -> bf16 ----------------
__global__ void cast_kernel(const float* __restrict__ in,
                            unsigned short* __restrict__ out, int n) {
  int i = (blockIdx.x * blockDim.x + threadIdx.x) * 4;
  if (i >= n) return;
  float4 v = *(const float4*)(in + i);
  ushort4 o;
  o.x = f2b(v.x); o.y = f2b(v.y); o.z = f2b(v.z); o.w = f2b(v.w);
  *(ushort4*)(out + i) = o;
}

// ---------------- transpose + cast weights: Wt[n][k] = W[k][n] ----------------
__global__ void trans_kernel(const float* __restrict__ w0, const float* __restrict__ w1,
                             const float* __restrict__ w2, const float* __restrict__ w3,
                             unsigned short* __restrict__ wt) {
  __shared__ float tile[32][33];
  const float* W = (blockIdx.z == 0) ? w0 : (blockIdx.z == 1) ? w1
                   : (blockIdx.z == 2) ? w2 : w3;
  unsigned short* Wt = wt + (size_t)blockIdx.z * DM * DM;
  const int tx = threadIdx.x & 31;
  const int ty = threadIdx.x >> 5;
  const int k0 = blockIdx.x * 32;
  const int c0 = blockIdx.y * 32;
#pragma unroll
  for (int i = 0; i < 4; ++i)
    tile[ty + i * 8][tx] = W[(size_t)(k0 + ty + i * 8) * DM + c0 + tx];
  __syncthreads();
#pragma unroll
  for (int i = 0; i < 4; ++i)
    Wt[(size_t)(c0 + ty + i * 8) * DM + k0 + tx] = f2b(tile[tx][ty + i * 8]);
}

// ---------------- RoPE table: tab[s][d2] = (cos, sin), d2 = d>>1 ----------------
__global__ void rope_kernel(float2* __restrict__ tab) {
  int i = blockIdx.x * 256 + threadIdx.x;  // 65536 = 2048*32
  int s = i >> 5, d2 = i & 31;
  float th = expf(-(float)d2 * (9.210340371976184f / 32.0f));
  float sn, cs;
  sincosf((float)s * th, &sn, &cs);
  tab[i] = make_float2(cs, sn);
}

// ---------------- fused QKV GEMM: BK=64, both-sides swizzle ----------------
// A[4096][1024] x Wt_qkv[3072][1024]^T. grid (32,24). mat = by>>3:
// 0=Q (RoPE + 0.125*log2e), 1=K (RoPE), 2=V. bf16 out [mat][bh][s][d].
__global__ __launch_bounds__(256, 3) void gemm_qkv(
    const unsigned short* __restrict__ A, const unsigned short* __restrict__ Wt,
    const float* __restrict__ bq, const float* __restrict__ bk,
    const float* __restrict__ bv, const float2* __restrict__ rope,
    unsigned short* __restrict__ QKV) {
  __shared__ __attribute__((aligned(16))) unsigned short As[128 * 64];
  __shared__ __attribute__((aligned(16))) unsigned short Bs[128 * 64];
  const int r0 = blockIdx.x * 128;
  const int c0 = blockIdx.y * 128;
  const int t = threadIdx.x;
  const int lane = t & 63;
  const int wv = t >> 6;
  const int wr = (wv >> 1) * 64;
  const int wc = (wv & 1) * 64;
  const int lr = lane & 15;
  const int lg = lane >> 4;

  // staging: wave wv stages rows [wv*32, +32); lane covers row lane>>3 of each
  // 8-row chunk, LDS seg = lane&7 (linear), global seg pre-swizzled ^ (row&7).
  const int srow = wv * 32 + (lane >> 3);
  const int sseg = ((lane & 7) ^ (lane >> 3)) * 8;
  const unsigned short* Ag = A + (size_t)(r0 + srow) * DM + sseg;
  const unsigned short* Bg = Wt + (size_t)(c0 + srow) * DM + sseg;
  unsigned short* lA = &As[wv * 32 * 64];
  unsigned short* lB = &Bs[wv * 32 * 64];

  floatx4 acc[4][4] = {};
  const int fswz = (lr & 7) << 4;

  for (int k0 = 0; k0 < DM; k0 += 64) {
#pragma unroll
    for (int j = 0; j < 4; ++j) {
      gload_lds16(Ag + k0 + j * 8 * DM, lA + j * 8 * 64);
      gload_lds16(Bg + k0 + j * 8 * DM, lB + j * 8 * 64);
    }
    __syncthreads();
#pragma unroll
    for (int kk = 0; kk < 2; ++kk) {
      short8 af[4], bf[4];
#pragma unroll
      for (int m = 0; m < 4; ++m)
        af[m] = *(const short8*)((char*)As + (wr + m * 16 + lr) * 128 +
                                 ((kk * 64 + lg * 16) ^ fswz));
#pragma unroll
      for (int n = 0; n < 4; ++n)
        bf[n] = *(const short8*)((char*)Bs + (wc + n * 16 + lr) * 128 +
                                 ((kk * 64 + lg * 16) ^ fswz));
#pragma unroll
      for (int m = 0; m < 4; ++m)
#pragma unroll
        for (int n = 0; n < 4; ++n)
          acc[m][n] = __builtin_amdgcn_mfma_f32_16x16x32_bf16(af[m], bf[n], acc[m][n], 0, 0, 0);
    }
    __syncthreads();
  }

  const int mat = blockIdx.y >> 3;
  const float* bias = (mat == 0) ? bq : (mat == 1) ? bk : bv;
  const int rbase = r0 + wr + lg * 4;
  const int cbase = c0 + wc + lr;
#pragma unroll
  for (int n = 0; n < 4; ++n) {
    const int c = cbase + n * 16;
    const int cc = c & (DM - 1);
    const float bvv = bias[cc];
    const int d = c & 63;
    const int h = cc >> 6;
#pragma unroll
    for (int m = 0; m < 4; ++m) {
#pragma unroll
      for (int i = 0; i < 4; ++i) {
        const int r = rbase + m * 16 + i;
        const int s = r & (S_ - 1);
        const int b = r >> 11;
        float v = acc[m][n][i] + bvv;
        float pv = __shfl_xor(v, 1);
        if (mat < 2) {
          float2 cssn = rope[s * 32 + (d >> 1)];
          v = (d & 1) ? fmaf(v, cssn.x, pv * cssn.y) : fmaf(v, cssn.x, -pv * cssn.y);
          if (mat == 0) v *= 0.18033688011112042f;  // 0.125 * log2(e)
        }
        QKV[((size_t)((mat << 5) | (b << 4) | h) * S_ + s) * HD + d] = f2b(v);
      }
    }
  }
}

// ---------------- out projection GEMM: BK=64 ----------------
__global__ __launch_bounds__(256, 3) void gemm_out(
    const unsigned short* __restrict__ A, const unsigned short* __restrict__ Wt,
    const float* __restrict__ bias, float* __restrict__ out) {
  __shared__ __attribute__((aligned(16))) unsigned short As[128 * 64];
  __shared__ __attribute__((aligned(16))) unsigned short Bs[128 * 64];
  const int r0 = blockIdx.x * 128;
  const int c0 = blockIdx.y * 128;
  const int t = threadIdx.x;
  const int lane = t & 63;
  const int wv = t >> 6;
  const int wr = (wv >> 1) * 64;
  const int wc = (wv & 1) * 64;
  const int lr = lane & 15;
  const int lg = lane >> 4;

  const int srow = wv * 32 + (lane >> 3);
  const int sseg = ((lane & 7) ^ (lane >> 3)) * 8;
  const unsigned short* Ag = A + (size_t)(r0 + srow) * DM + sseg;
  const unsigned short* Bg = Wt + (size_t)(c0 + srow) * DM + sseg;
  unsigned short* lA = &As[wv * 32 * 64];
  unsigned short* lB = &Bs[wv * 32 * 64];

  floatx4 acc[4][4] = {};
  const int fswz = (lr & 7) << 4;

  for (int k0 = 0; k0 < DM; k0 += 64) {
#pragma unroll
    for (int j = 0; j < 4; ++j) {
      gload_lds16(Ag + k0 + j * 8 * DM, lA + j * 8 * 64);
      gload_lds16(Bg + k0 + j * 8 * DM, lB + j * 8 * 64);
    }
    __syncthreads();
#pragma unroll
    for (int kk = 0; kk < 2; ++kk) {
      short8 af[4], bf[4];
#pragma unroll
      for (int m = 0; m < 4; ++m)
        af[m] = *(const short8*)((char*)As + (wr + m * 16 + lr) * 128 +
                                 ((kk * 64 + lg * 16) ^ fswz));
#pragma unroll
      for (int n = 0; n < 4; ++n)
        bf[n] = *(const short8*)((char*)Bs + (wc + n * 16 + lr) * 128 +
                                 ((kk * 64 + lg * 16) ^ fswz));
#pragma unroll
      for (int m = 0; m < 4; ++m)
#pragma unroll
        for (int n = 0; n < 4; ++n)
          acc[m][n] = __builtin_amdgcn_mfma_f32_16x16x32_bf16(af[m], bf[n], acc[m][n], 0, 0, 0);
    }
    __syncthreads();
  }

  const int rbase = r0 + wr + lg * 4;
  const int cbase = c0 + wc + lr;
#pragma unroll
  for (int n = 0; n < 4; ++n) {
    const int c = cbase + n * 16;
    const float bvv = bias[c];
#pragma unroll
    for (int m = 0; m < 4; ++m) {
#pragma unroll
      for (int i = 0; i < 4; ++i) {
        const int r = rbase + m * 16 + i;
        out[(size_t)r * DM + c] = acc[m][n][i] + bvv;
      }
    }
  }
}

// ---------------- MFMA flash attention v3: QBLK=128, 8 waves ----------------
// grid (bh=32, 16 q-tiles reversed), 512 thr. Wave w owns q rows
// [qt*128 + w*16, +16), q = lane&15. Swapped QK^T, lane-local softmax, exp2,
// defer-max (THR=8). Wave diag tile dt = 2qt + (w>>2); skip compute for t>dt.
__global__ __launch_bounds__(512, 4) void attn_kernel(
    const unsigned short* __restrict__ Q, const unsigned short* __restrict__ K,
    const unsigned short* __restrict__ V, unsigned short* __restrict__ AttnC) {
  __shared__ __attribute__((aligned(16))) unsigned short Ks[2][64 * 64];
  __shared__ __attribute__((aligned(16))) unsigned short Vs[2][64 * 64];
  __shared__ __attribute__((aligned(16))) unsigned short Ps[8][16 * 64];

  const int bh = blockIdx.x;
  const int qt = 15 - (int)blockIdx.y;  // big blocks first
  const int tid = threadIdx.x;
  const int w = tid >> 6;   // 0..7
  const int l = tid & 63;
  const int lg = l >> 4;    // 0..3
  const int lr = l & 15;    // q-row within wave tile
  const size_t base = (size_t)bh * S_ * HD;
  const int NT = 2 * qt + 2;
  const int dt = 2 * qt + (w >> 2);        // wave's diagonal tile
  const int qin = ((w & 3) << 4) + lr;     // q offset within its 64-key tile

  // Q as B-frag: B[k][q=lr] = Q[q][k], k = kk*32 + lg*8 + j
  short8 qf[2];
  {
    const unsigned short* Qrow =
        Q + base + (size_t)(qt * 128 + w * 16 + lr) * HD + lg * 8;
    qf[0] = *(const short8*)(Qrow);
    qf[1] = *(const short8*)(Qrow + 32);
  }

  floatx4 o[4] = {};
  float m = -1e30f, lsum = 0.f;  // per-lane q = lr (lsum is lg-partial)

  // staging roles (512 threads)
  const int krow = tid >> 3;                        // 0..63, one int4 of K
  const int kseg = tid & 7;
  const int kp = tid & 31;                          // V key-pair 2kp,2kp+1
  const int vd0 = ((tid >> 5) & 7) * 8 + (tid >> 8) * 4;  // 4 dims

  // prologue: load tile 0 into regs
  int4 kr;
  short4v va, vb;
  {
    const unsigned short* Kg = K + base;
    const unsigned short* Vg = V + base;
    kr = *(const int4*)(Kg + krow * 64 + kseg * 8);
    va = *(const short4v*)(Vg + 2 * kp * 64 + vd0);
    vb = *(const short4v*)(Vg + (2 * kp + 1) * 64 + vd0);
  }

  char* const Pw = (char*)Ps[w];
  const int pswz = (lr & 7) << 4;

  for (int t = 0; t < NT; ++t) {
    const int cur = t & 1;
    // (a) write regs (tile t) -> LDS[cur]
    {
      char* Kb = (char*)Ks[cur];
      *(int4*)(Kb + krow * 128 + ((kseg * 16) ^ ((krow & 7) << 4))) = kr;
      char* Vb = (char*)Vs[cur];
#pragma unroll
      for (int jj = 0; jj < 4; ++jj) {
        int d = vd0 + jj;
        unsigned int pk = (unsigned int)(unsigned short)va[jj] |
                          ((unsigned int)(unsigned short)vb[jj] << 16);
        *(unsigned int*)(Vb + d * 128 + ((4 * kp) ^ ((d & 7) << 4))) = pk;
      }
    }
    // (b) issue loads for tile t+1
    if (t + 1 < NT) {
      const unsigned short* Kg = K + base + (size_t)(t + 1) * 64 * HD;
      const unsigned short* Vg = V + base + (size_t)(t + 1) * 64 * HD;
      kr = *(const int4*)(Kg + krow * 64 + kseg * 8);
      va = *(const short4v*)(Vg + 2 * kp * 64 + vd0);
      vb = *(const short4v*)(Vg + (2 * kp + 1) * 64 + vd0);
    }
    // (c) one barrier (dbuf makes single barrier safe)
    __syncthreads();
    if (t > dt) continue;  // fully-masked tile for this wave: staging only

    // (d) S^T = K Q^T : s[n][i] = S[key = n*16+lg*4+i][q = lr]
    floatx4 s[4] = {};
    __builtin_amdgcn_s_setprio(1);
#pragma unroll
    for (int kk = 0; kk < 2; ++kk) {
#pragma unroll
      for (int n = 0; n < 4; ++n) {
        int r = n * 16 + lr;
        short8 kf = *(const short8*)((char*)Ks[cur] + r * 128 +
                                     ((kk * 64 + lg * 16) ^ ((r & 7) << 4)));
        s[n] = __builtin_amdgcn_mfma_f32_16x16x32_bf16(kf, qf[kk], s[n], 0, 0, 0);
      }
    }
    __builtin_amdgcn_s_setprio(0);
    if (t == dt) {  // causal: key_in_tile > q_in_tile
#pragma unroll
      for (int n = 0; n < 4; ++n)
#pragma unroll
        for (int i = 0; i < 4; ++i)
          if (n * 16 + lg * 4 + i > qin) s[n][i] = -1e30f;
    }

    // lane-local softmax for q = lr; cross-lane max over lanes lr+{0,16,32,48}
    float tm0 = fmaxf(fmaxf(s[0][0], s[0][1]), fmaxf(s[0][2], s[0][3]));
    float tm1 = fmaxf(fmaxf(s[1][0], s[1][1]), fmaxf(s[1][2], s[1][3]));
    float tm2 = fmaxf(fmaxf(s[2][0], s[2][1]), fmaxf(s[2][2], s[2][3]));
    float tm3 = fmaxf(fmaxf(s[3][0], s[3][1]), fmaxf(s[3][2], s[3][3]));
    float tm = fmaxf(fmaxf(tm0, tm1), fmaxf(tm2, tm3));
    tm = fmaxf(tm, __shfl_xor(tm, 16));
    tm = fmaxf(tm, __shfl_xor(tm, 32));
    // defer-max: only rescale when the tile max grew past m + 8 (exp2 domain)
    if (__any(tm > m + 8.f)) {
      const float mn = fmaxf(m, tm);
      const float al = exp2f(m - mn);
      m = mn;
      lsum *= al;
#pragma unroll
      for (int dd = 0; dd < 4; ++dd) o[dd] *= al;
    }
    float ps = 0.f;
#pragma unroll
    for (int n = 0; n < 4; ++n) {
#pragma unroll
      for (int i = 0; i < 4; ++i) {
        float p = exp2f(s[n][i] - m);
        s[n][i] = p;
        ps += p;
      }
    }
    lsum += ps;

    // write P^T rows into Ps[w]: row = q = lr, col k = n*16+lg*4+{0..3}
#pragma unroll
    for (int n = 0; n < 4; ++n) {
#pragma unroll
      for (int h = 0; h < 2; ++h) {
        unsigned int pk = (unsigned int)f2b(s[n][2 * h]) |
                          ((unsigned int)f2b(s[n][2 * h + 1]) << 16);
        *(unsigned int*)(Pw + lr * 128 + (((n * 16 + lg * 4 + 2 * h) * 2) ^ pswz)) = pk;
      }
    }
    // P^T as B-frag: B[k][q=lr], k = kk*32 + lg*8 + j
    short8 pb[2];
#pragma unroll
    for (int kk = 0; kk < 2; ++kk)
      pb[kk] = *(const short8*)(Pw + lr * 128 + ((kk * 64 + lg * 16) ^ pswz));
    // O^T += V^T P^T : A = Vt rows d = dd*16+lr
    __builtin_amdgcn_s_setprio(1);
#pragma unroll
    for (int kk = 0; kk < 2; ++kk)
#pragma unroll
      for (int dd = 0; dd < 4; ++dd) {
        int d = dd * 16 + lr;
        short8 vbf = *(const short8*)((char*)Vs[cur] + d * 128 +
                                      ((kk * 64 + lg * 16) ^ ((d & 7) << 4)));
        o[dd] = __builtin_amdgcn_mfma_f32_16x16x32_bf16(vbf, pb[kk], o[dd], 0, 0, 0);
      }
    __builtin_amdgcn_s_setprio(0);
  }

  // reduce lsum across the 4 lg-partials, write O[q=lr][d=dd*16+lg*4+i]
  lsum += __shfl_xor(lsum, 16);
  lsum += __shfl_xor(lsum, 32);
  const float inv = 1.f / lsum;
  unsigned short* orow =
      AttnC + (size_t)((bh >> 4) * S_ + qt * 128 + w * 16 + lr) * DM + (bh & 15) * HD;
#pragma unroll
  for (int dd = 0; dd < 4; ++dd) {
    unsigned int w0 = (unsigned int)f2b(o[dd][0] * inv) |
                      ((unsigned int)f2b(o[dd][1] * inv) << 16);
    unsigned int w1 = (unsigned int)f2b(o[dd][2] * inv) |
                      ((unsigned int)f2b(o[dd][3] * inv) << 16);
    *(uint2*)(orow + dd * 16 + lg * 4) = make_uint2(w0, w1);
  }
}

extern "C" void kernel_launch(void* const* d_in, const int* in_sizes, int n_in,
                              void* d_out, int out_size, void* d_ws, size_t ws_size,
                              hipStream_t stream) {
  const float* x = (const float*)d_in[0];
  const float* wq = (const float*)d_in[2];
  const float* bq = (const float*)d_in[3];
  const float* wk = (const float*)d_in[4];
  const float* bk = (const float*)d_in[5];
  const float* wv = (const float*)d_in[6];
  const float* bv = (const float*)d_in[7];
  const float* wo = (const float*)d_in[8];
  const float* bo = (const float*)d_in[9];

  char* ws = (char*)d_ws;
  const size_t MB = 1024ull * 1024ull;
  unsigned short* Xc = (unsigned short*)(ws);             // 8 MB
  unsigned short* Wt = (unsigned short*)(ws + 8 * MB);    // 4 x 2 MB
  unsigned short* QKVb = (unsigned short*)(ws + 16 * MB); // 24 MB
  unsigned short* Ac = (unsigned short*)(ws + 40 * MB);   // 8 MB
  float2* rope = (float2*)(ws + 48 * MB);                 // 0.5 MB

  cast_kernel<<<4096, 256, 0, stream>>>(x, Xc, 2 * S_ * DM);
  trans_kernel<<<dim3(32, 32, 4), 256, 0, stream>>>(wq, wk, wv, wo, Wt);
  rope_kernel<<<256, 256, 0, stream>>>(rope);
  gemm_qkv<<<dim3(32, 24), 256, 0, stream>>>(Xc, Wt, bq, bk, bv, rope, QKVb);
  attn_kernel<<<dim3(32, 16), 512, 0, stream>>>(
      QKVb, QKVb + 32ull * S_ * HD, QKVb + 64ull * S_ * HD, Ac);
  gemm_out<<<dim3(32, 8), 256, 0, stream>>>(Ac, Wt + 3ull * DM * DM, bo, (float*)d_out);
}